// Round 7
// baseline (719.004 us; speedup 1.0000x reference)
//
#include <hip/hip_runtime.h>
#include <hip/hip_bf16.h>
#include <math.h>

// ---------------------------------------------------------------------------
// NasAutoGraphC round 7.
// r6 post-mortem: top dispatch = pre-GEMM (81us) at Occupancy 23.7% == the
// grid ceiling (625 blocks x 4 waves / 8192 slots = 30.5%), MfmaUtil 7.4%,
// runtime-K loop -> no unroll, ~1 outstanding fragment. Latency-bound.
// This round:
//   * GEMM BM 64->32 (wave tile 16x64, 2m x 2n): grid 1250, occ cap 61%.
//   * K is a template param + unroll-4: loads hoisted, per-wave MLP.
//   * cls_mfma 128->64 rows/block: grid 625.
// Carried: packed hi/lo bf16 activations, 3x mfma_16x16x32_bf16 split
// product, merged weights (lin1@pre2, lin2@cls), no-LDS MFMA GEMMs,
// 3-phase scan, CSR aggregation.
// ---------------------------------------------------------------------------

typedef __attribute__((ext_vector_type(8))) short bf16x8;
typedef __attribute__((ext_vector_type(4))) float f32x4;

__device__ __forceinline__ float leaky01(float v) {
    return v > 0.f ? v : 0.01f * v;
}

// ---- packed hi/lo bf16 helpers ---------------------------------------------

__device__ __forceinline__ uint32_t rne_bf16(float f) {
    uint32_t u = __float_as_uint(f);
    return (u + 0x7FFFu + ((u >> 16) & 1u)) >> 16;
}
__device__ __forceinline__ uint32_t pack_hilo(float v) {
    uint32_t h = rne_bf16(v);
    float hf = __uint_as_float(h << 16);
    uint32_t l = rne_bf16(v - hf);
    return (h << 16) | l;
}
__device__ __forceinline__ float unpack_hilo(uint32_t p) {
    return __uint_as_float(p & 0xFFFF0000u) + __uint_as_float(p << 16);
}

struct FragPair { bf16x8 hi, lo; };

__device__ __forceinline__ FragPair load_packed_frag(const uint32_t* p) {
    uint4 a = *(const uint4*)p;
    uint4 b = *(const uint4*)(p + 4);
    uint32_t q[8] = {a.x, a.y, a.z, a.w, b.x, b.y, b.z, b.w};
    union { uint32_t u[4]; bf16x8 v; } h, lo;
    #pragma unroll
    for (int i = 0; i < 4; ++i) {
        h.u[i]  = (q[2*i] >> 16)      | (q[2*i+1] & 0xFFFF0000u);
        lo.u[i] = (q[2*i] & 0xFFFFu)  | (q[2*i+1] << 16);
    }
    FragPair r; r.hi = h.v; r.lo = lo.v; return r;
}

__device__ __forceinline__ FragPair cvt_frag_f32(const float* p) {
    float4 a = *(const float4*)p;
    float4 b = *(const float4*)(p + 4);
    float f[8] = {a.x, a.y, a.z, a.w, b.x, b.y, b.z, b.w};
    uint32_t hb[8], lb[8];
    #pragma unroll
    for (int i = 0; i < 8; ++i) {
        hb[i] = rne_bf16(f[i]);
        lb[i] = rne_bf16(f[i] - __uint_as_float(hb[i] << 16));
    }
    union { uint32_t u[4]; bf16x8 v; } h, lo;
    #pragma unroll
    for (int i = 0; i < 4; ++i) {
        h.u[i]  = hb[2*i] | (hb[2*i+1] << 16);
        lo.u[i] = lb[2*i] | (lb[2*i+1] << 16);
    }
    FragPair r; r.hi = h.v; r.lo = lo.v; return r;
}

// ---- graph preprocessing ---------------------------------------------------

__global__ void init_nodes(float* __restrict__ deg, int* __restrict__ cnt,
                           float* __restrict__ loop_w, int n) {
    int i = blockIdx.x * blockDim.x + threadIdx.x;
    if (i < n) { deg[i] = 0.f; cnt[i] = 0; loop_w[i] = 1.0f; }
}

__global__ void edge_pass1(const int* __restrict__ src, const int* __restrict__ dst,
                           const float* __restrict__ ew, float* __restrict__ deg,
                           int* __restrict__ cnt, float* __restrict__ loop_w, int E) {
    int e = blockIdx.x * blockDim.x + threadIdx.x;
    if (e >= E) return;
    int s = src[e], d = dst[e];
    float w = ew[e];
    if (s == d) {
        loop_w[s] = w;                      // PyG keeps existing loop weight
    } else {
        atomicAdd(&deg[s], w);
        atomicAdd(&cnt[d], 1);
    }
}

// ---- 3-phase scan: per-block partial scan -> top scan -> add base ----------

__global__ __launch_bounds__(1024) void scan_blocks(
    const int* __restrict__ cnt, const float* __restrict__ deg,
    int* __restrict__ partial, int* __restrict__ bsum,
    float* __restrict__ dis, int n)
{
    __shared__ int wsum[16];
    const int tid  = threadIdx.x;
    const int lane = tid & 63;
    const int wv   = tid >> 6;
    const int i    = (blockIdx.x << 10) + tid;
    int v = (i < n) ? cnt[i] : 0;
    if (i < n) {
        float d = deg[i];
        dis[i] = (d > 0.f) ? (1.0f / sqrtf(d)) : 0.f;
    }
    int incl = v;
    #pragma unroll
    for (int off = 1; off < 64; off <<= 1) {
        int t = __shfl_up(incl, off);
        if (lane >= off) incl += t;
    }
    if (lane == 63) wsum[wv] = incl;
    __syncthreads();
    if (tid < 16) {
        int s = wsum[tid];
        #pragma unroll
        for (int off = 1; off < 16; off <<= 1) {
            int u = __shfl_up(s, off);
            if (tid >= off) s += u;
        }
        wsum[tid] = s;
    }
    __syncthreads();
    int excl = (wv ? wsum[wv - 1] : 0) + incl - v;
    if (i < n) partial[i] = excl;
    if (tid == 0) bsum[blockIdx.x] = wsum[15];
}

// nb <= 64 required (N=40000 -> nb=40)
__global__ void scan_tops(const int* __restrict__ bsum, int* __restrict__ bbase,
                          int* __restrict__ offsets, int nb, int n) {
    const int tid = threadIdx.x;                 // 64 threads
    int v = (tid < nb) ? bsum[tid] : 0;
    int incl = v;
    #pragma unroll
    for (int off = 1; off < 64; off <<= 1) {
        int t = __shfl_up(incl, off);
        if (tid >= off) incl += t;
    }
    if (tid < nb) bbase[tid] = incl - v;
    if (tid == 63) offsets[n] = incl;            // grand total
}

__global__ void scan_add(int* __restrict__ offsets, int* __restrict__ cursor,
                         const int* __restrict__ bbase, int n) {
    int i = blockIdx.x * blockDim.x + threadIdx.x;
    if (i >= n) return;
    int v = offsets[i] + bbase[i >> 10];
    offsets[i] = v;
    cursor[i]  = v;
}

__global__ void edge_pass2(const int* __restrict__ src, const int* __restrict__ dst,
                           const float* __restrict__ ew, const float* __restrict__ dis,
                           int* __restrict__ cursor, int* __restrict__ slot_src,
                           float* __restrict__ slot_norm, float* __restrict__ slot_we,
                           int E) {
    int e = blockIdx.x * blockDim.x + threadIdx.x;
    if (e >= E) return;
    int s = src[e], d = dst[e];
    if (s == d) return;
    float w = ew[e];
    float nrm = -dis[s] * w * dis[d];
    int pos = atomicAdd(&cursor[d], 1);
    slot_src[pos]  = s;
    slot_norm[pos] = nrm;
    slot_we[pos]   = w;
}

// ---- weight merge (fp32, tiny) ---------------------------------------------

__global__ void merge_weights(const float* __restrict__ A, const float* __restrict__ B,
                              const float* __restrict__ ba, const float* __restrict__ bb,
                              float* __restrict__ Wm, float* __restrict__ bm,
                              int KA, int NB) {
    int idx = blockIdx.x * blockDim.x + threadIdx.x;
    int total = (KA + 1) * NB;
    if (idx >= total) return;
    int r = idx / NB, j = idx - r * NB;
    const float* arow = (r < KA) ? &A[(size_t)r * KA] : ba;
    float acc = 0.f;
    for (int q = 0; q < KA; ++q)
        acc = fmaf(arow[q], B[(size_t)q * NB + j], acc);
    if (r < KA) Wm[(size_t)r * NB + j] = acc;
    else        bm[j] = acc + bb[j];
}

// ---- weight convert: fp32 [K][128] -> packed TRANSPOSED [col][K] -----------
// segs: pre_w1 (K=512, 128 cols) + 7x (K=128, 128 cols) + cls (K=128, 48
// cols, src stride 40, zero-pad cols >= 40).

#define WT_TOTAL (65536 + 7 * 16384 + 48 * 128)

__global__ void convert_weights(const float* s0, const float* s1, const float* s2,
                                const float* s3, const float* s4, const float* s5,
                                const float* s6, const float* s7, const float* s8,
                                uint32_t* __restrict__ dst) {
    int idx = blockIdx.x * blockDim.x + threadIdx.x;
    if (idx >= WT_TOTAL) return;
    if (idx >= 65536 + 7 * 16384) {              // cls segment: [48][128]
        int local = idx - (65536 + 7 * 16384);
        int col = local >> 7, k = local & 127;
        float v = (col < 40) ? s8[(size_t)k * 40 + col] : 0.f;
        dst[idx] = pack_hilo(v);
        return;
    }
    const float* src; int K, local; uint32_t* d;
    if (idx < 65536) { src = s0; K = 512; local = idx; d = dst; }
    else {
        int t = idx - 65536;
        int seg = t >> 14; local = t & 16383; K = 128;
        d = dst + 65536 + (seg << 14);
        src = seg == 0 ? s1 : seg == 1 ? s2 : seg == 2 ? s3 :
              seg == 3 ? s4 : seg == 4 ? s5 : seg == 5 ? s6 : s7;
    }
    int col = local / K, k = local - col * K;
    d[local] = pack_hilo(src[(size_t)k * 128 + col]);
}

// ---- aggregation (packed IO): wave per node, 2-edge unrolled ---------------

__global__ __launch_bounds__(256) void aggregate_packed(
    const uint32_t* __restrict__ xh, const int* __restrict__ offsets,
    const int* __restrict__ slot_src, const float* __restrict__ slot_norm,
    const float* __restrict__ slot_we, const float* __restrict__ loop_w,
    const int* __restrict__ cnt, uint32_t* __restrict__ tx1,
    uint32_t* __restrict__ sagg, int n)
{
    const int lane = threadIdx.x & 63;
    const int wv   = threadIdx.x >> 6;
    const int node = (blockIdx.x << 2) + wv;
    if (node >= n) return;
    const int beg = offsets[node], end = offsets[node + 1];
    const int c = lane << 1;
    float ax = 0.f, ay = 0.f, sx = 0.f, sy = 0.f;
    float ax2 = 0.f, ay2 = 0.f, sx2 = 0.f, sy2 = 0.f;
    int e = beg;
    for (; e + 1 < end; e += 2) {
        const int   s0 = slot_src[e],     s1 = slot_src[e + 1];
        const float n0 = slot_norm[e],    n1 = slot_norm[e + 1];
        const float w0 = slot_we[e],      w1 = slot_we[e + 1];
        const uint2 p0 = *(const uint2*)&xh[((size_t)s0 << 7) + c];
        const uint2 p1 = *(const uint2*)&xh[((size_t)s1 << 7) + c];
        const float v0x = unpack_hilo(p0.x), v0y = unpack_hilo(p0.y);
        const float v1x = unpack_hilo(p1.x), v1y = unpack_hilo(p1.y);
        ax  = fmaf(n0, v0x, ax);  ay  = fmaf(n0, v0y, ay);
        sx  = fmaf(w0, v0x, sx);  sy  = fmaf(w0, v0y, sy);
        ax2 = fmaf(n1, v1x, ax2); ay2 = fmaf(n1, v1y, ay2);
        sx2 = fmaf(w1, v1x, sx2); sy2 = fmaf(w1, v1y, sy2);
    }
    if (e < end) {
        const int   s0 = slot_src[e];
        const float n0 = slot_norm[e];
        const float w0 = slot_we[e];
        const uint2 p0 = *(const uint2*)&xh[((size_t)s0 << 7) + c];
        const float v0x = unpack_hilo(p0.x), v0y = unpack_hilo(p0.y);
        ax = fmaf(n0, v0x, ax); ay = fmaf(n0, v0y, ay);
        sx = fmaf(w0, v0x, sx); sy = fmaf(w0, v0y, sy);
    }
    ax += ax2; ay += ay2; sx += sx2; sy += sy2;
    const uint2 ps = *(const uint2*)&xh[((size_t)node << 7) + c];
    const float lw = loop_w[node];
    sx = fmaf(lw, unpack_hilo(ps.x), sx); sy = fmaf(lw, unpack_hilo(ps.y), sy);
    const float inv = 1.0f / (float)(cnt[node] + 1);
    *(uint2*)&tx1[((size_t)node << 7) + c]  =
        make_uint2(pack_hilo(ax), pack_hilo(ay));
    *(uint2*)&sagg[((size_t)node << 7) + c] =
        make_uint2(pack_hilo(sx * inv), pack_hilo(sy * inv));
}

// ---- split-bf16 MFMA GEMM (no LDS, no barriers) ----------------------------
// Wave tile 16 rows x 64 cols; block = 4 waves (2m x 2n) = 32 rows x 128 cols.
// K compile-time -> unrolled loads hoisted ahead of MFMAs (per-wave MLP).

template<bool F32, int K>
__device__ __forceinline__ void gemm_part(
    const void* Av, const uint32_t* __restrict__ Wt,
    int rbase, int cbase, int l15, int kg, f32x4 acc[4])
{
    const int row = rbase + l15;
    #pragma unroll 4
    for (int k = 0; k < K; k += 32) {
        FragPair Af;
        if constexpr (F32)
            Af = cvt_frag_f32((const float*)Av + (size_t)row * K + k + kg * 8);
        else
            Af = load_packed_frag((const uint32_t*)Av + (size_t)row * K + k + kg * 8);
        #pragma unroll
        for (int n = 0; n < 4; ++n) {
            const FragPair Bf =
                load_packed_frag(Wt + (size_t)(cbase + n * 16 + l15) * K + k + kg * 8);
            acc[n] = __builtin_amdgcn_mfma_f32_16x16x32_bf16(Af.hi, Bf.hi, acc[n], 0, 0, 0);
            acc[n] = __builtin_amdgcn_mfma_f32_16x16x32_bf16(Af.hi, Bf.lo, acc[n], 0, 0, 0);
            acc[n] = __builtin_amdgcn_mfma_f32_16x16x32_bf16(Af.lo, Bf.hi, acc[n], 0, 0, 0);
        }
    }
}

// NPARTS=1: out = A1@W1 + b1
// NPARTS=3: out = leaky(A1@W1 + A2@W2 + b1) + leaky(A3@W3 + b2)
template<int NPARTS, bool AF32, int K1>
__global__ __launch_bounds__(256, 4) void gemm_mfma(
    const void* __restrict__ A1, const uint32_t* __restrict__ Wt1,
    const uint32_t* __restrict__ A2, const uint32_t* __restrict__ Wt2,
    const uint32_t* __restrict__ A3, const uint32_t* __restrict__ Wt3,
    const float* __restrict__ b1, const float* __restrict__ b2,
    uint32_t* __restrict__ out, int M)
{
    const int tid  = threadIdx.x;
    const int lane = tid & 63;
    const int w    = tid >> 6;
    const int mw   = w >> 1, nw = w & 1;
    const int l15  = lane & 15;
    const int kg   = lane >> 4;
    const int rbase = blockIdx.x * 32 + mw * 16;  // M divisible by 32
    const int cbase = nw * 64;

    f32x4 accA[4];
    #pragma unroll
    for (int n = 0; n < 4; ++n) accA[n] = (f32x4)0.f;

    gemm_part<AF32, K1>(A1, Wt1, rbase, cbase, l15, kg, accA);

    if constexpr (NPARTS == 3) {
        gemm_part<false, 128>(A2, Wt2, rbase, cbase, l15, kg, accA);
        f32x4 accB[4];
        #pragma unroll
        for (int n = 0; n < 4; ++n) accB[n] = (f32x4)0.f;
        gemm_part<false, 128>(A3, Wt3, rbase, cbase, l15, kg, accB);

        #pragma unroll
        for (int n = 0; n < 4; ++n) {
            const int col = cbase + n * 16 + l15;
            const float bb1 = b1[col], bb2 = b2[col];
            #pragma unroll
            for (int r = 0; r < 4; ++r) {
                const int row = rbase + kg * 4 + r;
                float v = leaky01(accA[n][r] + bb1) + leaky01(accB[n][r] + bb2);
                out[(size_t)row * 128 + col] = pack_hilo(v);
            }
        }
    } else {
        #pragma unroll
        for (int n = 0; n < 4; ++n) {
            const int col = cbase + n * 16 + l15;
            const float bb1 = b1[col];
            #pragma unroll
            for (int r = 0; r < 4; ++r) {
                const int row = rbase + kg * 4 + r;
                out[(size_t)row * 128 + col] = pack_hilo(accA[n][r] + bb1);
            }
        }
    }
    (void)M;
}

// ---- classifier: split-bf16 MFMA + fused log_softmax -----------------------
// Wt padded to 48 cols (cols 40..47 zero). Block = 4 waves x 16 rows = 64
// rows (grid 625). C/D layout col=n*16+l15, row=kg*4+r: a full logit row
// lives in one 16-lane group -> shfl_xor{1,2,4,8} row reductions, no LDS.

__global__ __launch_bounds__(256) void cls_mfma(
    const uint32_t* __restrict__ x2, const uint32_t* __restrict__ Wt,
    const float* __restrict__ bias, float* __restrict__ out, int M)
{
    const int tid  = threadIdx.x;
    const int lane = tid & 63;
    const int w    = tid >> 6;
    const int l15  = lane & 15;
    const int kg   = lane >> 4;
    const int rbase = blockIdx.x * 64 + w * 16;   // M divisible by 64

    f32x4 acc[3];
    #pragma unroll
    for (int n = 0; n < 3; ++n) acc[n] = (f32x4)0.f;

    const int arow = rbase + l15;
    #pragma unroll
    for (int k = 0; k < 128; k += 32) {
        const FragPair Af = load_packed_frag(x2 + (size_t)arow * 128 + k + kg * 8);
        #pragma unroll
        for (int n = 0; n < 3; ++n) {
            const FragPair Bf =
                load_packed_frag(Wt + (size_t)(n * 16 + l15) * 128 + k + kg * 8);
            acc[n] = __builtin_amdgcn_mfma_f32_16x16x32_bf16(Af.hi, Bf.hi, acc[n], 0, 0, 0);
            acc[n] = __builtin_amdgcn_mfma_f32_16x16x32_bf16(Af.hi, Bf.lo, acc[n], 0, 0, 0);
            acc[n] = __builtin_amdgcn_mfma_f32_16x16x32_bf16(Af.lo, Bf.hi, acc[n], 0, 0, 0);
        }
    }

    const bool v2 = (l15 < 8);                   // col 32+l15 < 40
    const float bv0 = bias[l15];
    const float bv1 = bias[16 + l15];
    const float bv2 = v2 ? bias[32 + l15] : 0.f;

    #pragma unroll
    for (int r = 0; r < 4; ++r) {
        const int row = rbase + kg * 4 + r;
        float x0 = acc[0][r] + bv0;
        float x1 = acc[1][r] + bv1;
        float x2v = v2 ? (acc[2][r] + bv2) : -INFINITY;
        float mx = fmaxf(fmaxf(x0, x1), x2v);
        #pragma unroll
        for (int off = 1; off < 16; off <<= 1)
            mx = fmaxf(mx, __shfl_xor(mx, off));
        float s = __expf(x0 - mx) + __expf(x1 - mx) + (v2 ? __expf(x2v - mx) : 0.f);
        #pragma unroll
        for (int off = 1; off < 16; off <<= 1)
            s += __shfl_xor(s, off);
        const float ls = logf(s);
        if (row < M) {
            float* op = &out[(size_t)row * 40];
            op[l15]      = x0 - mx - ls;
            op[16 + l15] = x1 - mx - ls;
            if (v2) op[32 + l15] = x2v - mx - ls;
        }
    }
}

// ---------------------------------------------------------------------------

extern "C" void kernel_launch(void* const* d_in, const int* in_sizes, int n_in,
                              void* d_out, int out_size, void* d_ws, size_t ws_size,
                              hipStream_t stream)
{
    const float* x        = (const float*)d_in[0];
    const int*   ei       = (const int*)d_in[1];
    const float* ew       = (const float*)d_in[2];
    const float* pre_w1   = (const float*)d_in[3];
    const float* pre_b1   = (const float*)d_in[4];
    const float* cheb_w01 = (const float*)d_in[5];
    const float* cheb_w11 = (const float*)d_in[6];
    const float* cheb_b1  = (const float*)d_in[7];
    const float* sage_w1  = (const float*)d_in[8];
    const float* sage_b1  = (const float*)d_in[9];
    const float* lin_w1   = (const float*)d_in[10];
    const float* lin_b1   = (const float*)d_in[11];
    const float* pre_w2   = (const float*)d_in[12];
    const float* pre_b2   = (const float*)d_in[13];
    const float* cheb_w02 = (const float*)d_in[14];
    const float* cheb_w12 = (const float*)d_in[15];
    const float* cheb_b2  = (const float*)d_in[16];
    const float* sage_w2  = (const float*)d_in[17];
    const float* sage_b2  = (const float*)d_in[18];
    const float* lin_w2   = (const float*)d_in[19];
    const float* lin_b2   = (const float*)d_in[20];
    const float* cls_w    = (const float*)d_in[21];
    const float* cls_b    = (const float*)d_in[22];

    const int H    = 128;
    const int F_IN = in_sizes[3] / H;       // 512
    const int N    = in_sizes[0] / F_IN;    // 40000
    const int E    = in_sizes[2];           // 640000
    const int* src = ei;
    const int* dst = ei + E;

    // workspace carve-up (256B aligned)
    char* p = (char*)d_ws;
    auto alloc = [&](size_t bytes) -> void* {
        void* r = (void*)p;
        p += (bytes + 255) & ~(size_t)255;
        return r;
    };
    uint32_t* buf0 = (uint32_t*)alloc((size_t)N * 128 * 4);   // packed activations
    uint32_t* buf1 = (uint32_t*)alloc((size_t)N * 128 * 4);
    uint32_t* buf2 = (uint32_t*)alloc((size_t)N * 128 * 4);
    uint32_t* buf3 = (uint32_t*)alloc((size_t)N * 128 * 4);
    float* deg     = (float*)alloc((size_t)N * 4);
    float* dis     = (float*)alloc((size_t)N * 4);
    float* loop_w  = (float*)alloc((size_t)N * 4);
    int*   cnt     = (int*)alloc((size_t)N * 4);
    int*   offs    = (int*)alloc((size_t)(N + 1) * 4);
    int*   cursor  = (int*)alloc((size_t)N * 4);
    int*   bsum    = (int*)alloc(64 * 4);
    int*   bbase   = (int*)alloc(64 * 4);
    int*   slot_src  = (int*)alloc((size_t)E * 4);
    float* slot_nrm  = (float*)alloc((size_t)E * 4);
    float* slot_we   = (float*)alloc((size_t)E * 4);
    float* Wm1 = (float*)alloc((size_t)H * H * 4);    // lin_w1 @ pre_w2 (fp32)
    float* bm1 = (float*)alloc((size_t)H * 4);
    float* Wm2 = (float*)alloc((size_t)H * 40 * 4);   // lin_w2 @ cls_w (fp32)
    float* bm2 = (float*)alloc((size_t)40 * 4);
    uint32_t* wt = (uint32_t*)alloc((size_t)WT_TOTAL * 4);    // packed W^T
    (void)ws_size; (void)n_in; (void)out_size;

    uint32_t* wt_pre  = wt;                 // [128][512]
    uint32_t* wt_cw01 = wt + 65536;
    uint32_t* wt_cw11 = wt_cw01 + 16384;
    uint32_t* wt_sw1  = wt_cw11 + 16384;
    uint32_t* wt_Wm1  = wt_sw1  + 16384;
    uint32_t* wt_cw02 = wt_Wm1  + 16384;
    uint32_t* wt_cw12 = wt_cw02 + 16384;
    uint32_t* wt_sw2  = wt_cw12 + 16384;
    uint32_t* wt_cls  = wt_sw2  + 16384;    // [48][128]

    const int nb_n = (N + 255) / 256;
    const int nb_e = (E + 255) / 256;
    const int nb_w = (N + 3) / 4;           // wave-per-node kernels
    const int nb_g = (N + 31) / 32;         // MFMA GEMM blocks (1250)
    const int nb_s = (N + 1023) / 1024;     // scan blocks (40)
    const int nb_c = (N + 63) / 64;         // cls blocks (625)

    // graph preprocessing + weight merge/convert
    init_nodes<<<nb_n, 256, 0, stream>>>(deg, cnt, loop_w, N);
    edge_pass1<<<nb_e, 256, 0, stream>>>(src, dst, ew, deg, cnt, loop_w, E);
    scan_blocks<<<nb_s, 1024, 0, stream>>>(cnt, deg, offs, bsum, dis, N);
    scan_tops<<<1, 64, 0, stream>>>(bsum, bbase, offs, nb_s, N);
    scan_add<<<nb_n, 256, 0, stream>>>(offs, cursor, bbase, N);
    edge_pass2<<<nb_e, 256, 0, stream>>>(src, dst, ew, dis, cursor,
                                         slot_src, slot_nrm, slot_we, E);
    merge_weights<<<((H + 1) * H + 255) / 256, 256, 0, stream>>>(
        lin_w1, pre_w2, lin_b1, pre_b2, Wm1, bm1, H, H);
    merge_weights<<<((H + 1) * 40 + 255) / 256, 256, 0, stream>>>(
        lin_w2, cls_w, lin_b2, cls_b, Wm2, bm2, H, 40);
    convert_weights<<<(WT_TOTAL + 255) / 256, 256, 0, stream>>>(
        pre_w1, cheb_w01, cheb_w11, sage_w1, Wm1, cheb_w02, cheb_w12, sage_w2,
        Wm2, wt);

    // ---- cell 1 ----
    gemm_mfma<1, true, 512><<<nb_g, 256, 0, stream>>>(
        x, wt_pre, nullptr, nullptr, nullptr, nullptr,
        pre_b1, nullptr, buf0, N);
    aggregate_packed<<<nb_w, 256, 0, stream>>>(buf0, offs, slot_src, slot_nrm,
                                               slot_we, loop_w, cnt, buf1, buf2, N);
    gemm_mfma<3, false, 128><<<nb_g, 256, 0, stream>>>(
        buf0, wt_cw01, buf1, wt_cw11, buf2, wt_sw1,
        cheb_b1, sage_b1, buf3, N);
    gemm_mfma<1, false, 128><<<nb_g, 256, 0, stream>>>(
        buf3, wt_Wm1, nullptr, nullptr, nullptr, nullptr,
        bm1, nullptr, buf0, N);

    // ---- cell 2 ----
    aggregate_packed<<<nb_w, 256, 0, stream>>>(buf0, offs, slot_src, slot_nrm,
                                               slot_we, loop_w, cnt, buf1, buf2, N);
    gemm_mfma<3, false, 128><<<nb_g, 256, 0, stream>>>(
        buf0, wt_cw02, buf1, wt_cw12, buf2, wt_sw2,
        cheb_b2, sage_b2, buf3, N);

    // classifier (merged lin2+cls, MFMA) + fused log_softmax -> d_out
    cls_mfma<<<nb_c, 256, 0, stream>>>(buf3, wt_cls, bm2, (float*)d_out, N);
}

// Round 8
// 638.204 us; speedup vs baseline: 1.1266x; 1.1266x over previous
//
#include <hip/hip_runtime.h>
#include <hip/hip_bf16.h>
#include <math.h>

// ---------------------------------------------------------------------------
// NasAutoGraphC round 8.
// r7 post-mortem: lb(256,4) capped VGPR at 60 -> no loads in flight (MfmaUtil
// 4.9%); BM 32 halved per-wave arithmetic intensity vs L2. Both reverted.
// This round = r6 tile shape + funded pipeline:
//   * wave tile 32x64 (2 m-frags x 4 n-frags), block 2m x 2n waves = 64x128,
//     grid 625.
//   * __launch_bounds__(256, 2): VGPR cap 256 -> multi-k-step load hoisting.
//   * compile-time K, #pragma unroll (full): K=128 fully unrolled.
// Carried: packed hi/lo bf16 activations, 3x mfma_16x16x32_bf16 split
// product, merged weights (lin1@pre2, lin2@cls), cls_mfma + fused
// log_softmax, 3-phase scan, CSR aggregation.
// ---------------------------------------------------------------------------

typedef __attribute__((ext_vector_type(8))) short bf16x8;
typedef __attribute__((ext_vector_type(4))) float f32x4;

__device__ __forceinline__ float leaky01(float v) {
    return v > 0.f ? v : 0.01f * v;
}

// ---- packed hi/lo bf16 helpers ---------------------------------------------

__device__ __forceinline__ uint32_t rne_bf16(float f) {
    uint32_t u = __float_as_uint(f);
    return (u + 0x7FFFu + ((u >> 16) & 1u)) >> 16;
}
__device__ __forceinline__ uint32_t pack_hilo(float v) {
    uint32_t h = rne_bf16(v);
    float hf = __uint_as_float(h << 16);
    uint32_t l = rne_bf16(v - hf);
    return (h << 16) | l;
}
__device__ __forceinline__ float unpack_hilo(uint32_t p) {
    return __uint_as_float(p & 0xFFFF0000u) + __uint_as_float(p << 16);
}

struct FragPair { bf16x8 hi, lo; };

__device__ __forceinline__ FragPair load_packed_frag(const uint32_t* p) {
    uint4 a = *(const uint4*)p;
    uint4 b = *(const uint4*)(p + 4);
    uint32_t q[8] = {a.x, a.y, a.z, a.w, b.x, b.y, b.z, b.w};
    union { uint32_t u[4]; bf16x8 v; } h, lo;
    #pragma unroll
    for (int i = 0; i < 4; ++i) {
        h.u[i]  = (q[2*i] >> 16)      | (q[2*i+1] & 0xFFFF0000u);
        lo.u[i] = (q[2*i] & 0xFFFFu)  | (q[2*i+1] << 16);
    }
    FragPair r; r.hi = h.v; r.lo = lo.v; return r;
}

__device__ __forceinline__ FragPair cvt_frag_f32(const float* p) {
    float4 a = *(const float4*)p;
    float4 b = *(const float4*)(p + 4);
    float f[8] = {a.x, a.y, a.z, a.w, b.x, b.y, b.z, b.w};
    uint32_t hb[8], lb[8];
    #pragma unroll
    for (int i = 0; i < 8; ++i) {
        hb[i] = rne_bf16(f[i]);
        lb[i] = rne_bf16(f[i] - __uint_as_float(hb[i] << 16));
    }
    union { uint32_t u[4]; bf16x8 v; } h, lo;
    #pragma unroll
    for (int i = 0; i < 4; ++i) {
        h.u[i]  = hb[2*i] | (hb[2*i+1] << 16);
        lo.u[i] = lb[2*i] | (lb[2*i+1] << 16);
    }
    FragPair r; r.hi = h.v; r.lo = lo.v; return r;
}

// ---- graph preprocessing ---------------------------------------------------

__global__ void init_nodes(float* __restrict__ deg, int* __restrict__ cnt,
                           float* __restrict__ loop_w, int n) {
    int i = blockIdx.x * blockDim.x + threadIdx.x;
    if (i < n) { deg[i] = 0.f; cnt[i] = 0; loop_w[i] = 1.0f; }
}

__global__ void edge_pass1(const int* __restrict__ src, const int* __restrict__ dst,
                           const float* __restrict__ ew, float* __restrict__ deg,
                           int* __restrict__ cnt, float* __restrict__ loop_w, int E) {
    int e = blockIdx.x * blockDim.x + threadIdx.x;
    if (e >= E) return;
    int s = src[e], d = dst[e];
    float w = ew[e];
    if (s == d) {
        loop_w[s] = w;                      // PyG keeps existing loop weight
    } else {
        atomicAdd(&deg[s], w);
        atomicAdd(&cnt[d], 1);
    }
}

// ---- 3-phase scan: per-block partial scan -> top scan -> add base ----------

__global__ __launch_bounds__(1024) void scan_blocks(
    const int* __restrict__ cnt, const float* __restrict__ deg,
    int* __restrict__ partial, int* __restrict__ bsum,
    float* __restrict__ dis, int n)
{
    __shared__ int wsum[16];
    const int tid  = threadIdx.x;
    const int lane = tid & 63;
    const int wv   = tid >> 6;
    const int i    = (blockIdx.x << 10) + tid;
    int v = (i < n) ? cnt[i] : 0;
    if (i < n) {
        float d = deg[i];
        dis[i] = (d > 0.f) ? (1.0f / sqrtf(d)) : 0.f;
    }
    int incl = v;
    #pragma unroll
    for (int off = 1; off < 64; off <<= 1) {
        int t = __shfl_up(incl, off);
        if (lane >= off) incl += t;
    }
    if (lane == 63) wsum[wv] = incl;
    __syncthreads();
    if (tid < 16) {
        int s = wsum[tid];
        #pragma unroll
        for (int off = 1; off < 16; off <<= 1) {
            int u = __shfl_up(s, off);
            if (tid >= off) s += u;
        }
        wsum[tid] = s;
    }
    __syncthreads();
    int excl = (wv ? wsum[wv - 1] : 0) + incl - v;
    if (i < n) partial[i] = excl;
    if (tid == 0) bsum[blockIdx.x] = wsum[15];
}

// nb <= 64 required (N=40000 -> nb=40)
__global__ void scan_tops(const int* __restrict__ bsum, int* __restrict__ bbase,
                          int* __restrict__ offsets, int nb, int n) {
    const int tid = threadIdx.x;                 // 64 threads
    int v = (tid < nb) ? bsum[tid] : 0;
    int incl = v;
    #pragma unroll
    for (int off = 1; off < 64; off <<= 1) {
        int t = __shfl_up(incl, off);
        if (tid >= off) incl += t;
    }
    if (tid < nb) bbase[tid] = incl - v;
    if (tid == 63) offsets[n] = incl;            // grand total
}

__global__ void scan_add(int* __restrict__ offsets, int* __restrict__ cursor,
                         const int* __restrict__ bbase, int n) {
    int i = blockIdx.x * blockDim.x + threadIdx.x;
    if (i >= n) return;
    int v = offsets[i] + bbase[i >> 10];
    offsets[i] = v;
    cursor[i]  = v;
}

__global__ void edge_pass2(const int* __restrict__ src, const int* __restrict__ dst,
                           const float* __restrict__ ew, const float* __restrict__ dis,
                           int* __restrict__ cursor, int* __restrict__ slot_src,
                           float* __restrict__ slot_norm, float* __restrict__ slot_we,
                           int E) {
    int e = blockIdx.x * blockDim.x + threadIdx.x;
    if (e >= E) return;
    int s = src[e], d = dst[e];
    if (s == d) return;
    float w = ew[e];
    float nrm = -dis[s] * w * dis[d];
    int pos = atomicAdd(&cursor[d], 1);
    slot_src[pos]  = s;
    slot_norm[pos] = nrm;
    slot_we[pos]   = w;
}

// ---- weight merge (fp32, tiny) ---------------------------------------------

__global__ void merge_weights(const float* __restrict__ A, const float* __restrict__ B,
                              const float* __restrict__ ba, const float* __restrict__ bb,
                              float* __restrict__ Wm, float* __restrict__ bm,
                              int KA, int NB) {
    int idx = blockIdx.x * blockDim.x + threadIdx.x;
    int total = (KA + 1) * NB;
    if (idx >= total) return;
    int r = idx / NB, j = idx - r * NB;
    const float* arow = (r < KA) ? &A[(size_t)r * KA] : ba;
    float acc = 0.f;
    for (int q = 0; q < KA; ++q)
        acc = fmaf(arow[q], B[(size_t)q * NB + j], acc);
    if (r < KA) Wm[(size_t)r * NB + j] = acc;
    else        bm[j] = acc + bb[j];
}

// ---- weight convert: fp32 [K][128] -> packed TRANSPOSED [col][K] -----------
// segs: pre_w1 (K=512, 128 cols) + 7x (K=128, 128 cols) + cls (K=128, 48
// cols, src stride 40, zero-pad cols >= 40).

#define WT_TOTAL (65536 + 7 * 16384 + 48 * 128)

__global__ void convert_weights(const float* s0, const float* s1, const float* s2,
                                const float* s3, const float* s4, const float* s5,
                                const float* s6, const float* s7, const float* s8,
                                uint32_t* __restrict__ dst) {
    int idx = blockIdx.x * blockDim.x + threadIdx.x;
    if (idx >= WT_TOTAL) return;
    if (idx >= 65536 + 7 * 16384) {              // cls segment: [48][128]
        int local = idx - (65536 + 7 * 16384);
        int col = local >> 7, k = local & 127;
        float v = (col < 40) ? s8[(size_t)k * 40 + col] : 0.f;
        dst[idx] = pack_hilo(v);
        return;
    }
    const float* src; int K, local; uint32_t* d;
    if (idx < 65536) { src = s0; K = 512; local = idx; d = dst; }
    else {
        int t = idx - 65536;
        int seg = t >> 14; local = t & 16383; K = 128;
        d = dst + 65536 + (seg << 14);
        src = seg == 0 ? s1 : seg == 1 ? s2 : seg == 2 ? s3 :
              seg == 3 ? s4 : seg == 4 ? s5 : seg == 5 ? s6 : s7;
    }
    int col = local / K, k = local - col * K;
    d[local] = pack_hilo(src[(size_t)k * 128 + col]);
}

// ---- aggregation (packed IO): wave per node, 2-edge unrolled ---------------

__global__ __launch_bounds__(256) void aggregate_packed(
    const uint32_t* __restrict__ xh, const int* __restrict__ offsets,
    const int* __restrict__ slot_src, const float* __restrict__ slot_norm,
    const float* __restrict__ slot_we, const float* __restrict__ loop_w,
    const int* __restrict__ cnt, uint32_t* __restrict__ tx1,
    uint32_t* __restrict__ sagg, int n)
{
    const int lane = threadIdx.x & 63;
    const int wv   = threadIdx.x >> 6;
    const int node = (blockIdx.x << 2) + wv;
    if (node >= n) return;
    const int beg = offsets[node], end = offsets[node + 1];
    const int c = lane << 1;
    float ax = 0.f, ay = 0.f, sx = 0.f, sy = 0.f;
    float ax2 = 0.f, ay2 = 0.f, sx2 = 0.f, sy2 = 0.f;
    int e = beg;
    for (; e + 1 < end; e += 2) {
        const int   s0 = slot_src[e],     s1 = slot_src[e + 1];
        const float n0 = slot_norm[e],    n1 = slot_norm[e + 1];
        const float w0 = slot_we[e],      w1 = slot_we[e + 1];
        const uint2 p0 = *(const uint2*)&xh[((size_t)s0 << 7) + c];
        const uint2 p1 = *(const uint2*)&xh[((size_t)s1 << 7) + c];
        const float v0x = unpack_hilo(p0.x), v0y = unpack_hilo(p0.y);
        const float v1x = unpack_hilo(p1.x), v1y = unpack_hilo(p1.y);
        ax  = fmaf(n0, v0x, ax);  ay  = fmaf(n0, v0y, ay);
        sx  = fmaf(w0, v0x, sx);  sy  = fmaf(w0, v0y, sy);
        ax2 = fmaf(n1, v1x, ax2); ay2 = fmaf(n1, v1y, ay2);
        sx2 = fmaf(w1, v1x, sx2); sy2 = fmaf(w1, v1y, sy2);
    }
    if (e < end) {
        const int   s0 = slot_src[e];
        const float n0 = slot_norm[e];
        const float w0 = slot_we[e];
        const uint2 p0 = *(const uint2*)&xh[((size_t)s0 << 7) + c];
        const float v0x = unpack_hilo(p0.x), v0y = unpack_hilo(p0.y);
        ax = fmaf(n0, v0x, ax); ay = fmaf(n0, v0y, ay);
        sx = fmaf(w0, v0x, sx); sy = fmaf(w0, v0y, sy);
    }
    ax += ax2; ay += ay2; sx += sx2; sy += sy2;
    const uint2 ps = *(const uint2*)&xh[((size_t)node << 7) + c];
    const float lw = loop_w[node];
    sx = fmaf(lw, unpack_hilo(ps.x), sx); sy = fmaf(lw, unpack_hilo(ps.y), sy);
    const float inv = 1.0f / (float)(cnt[node] + 1);
    *(uint2*)&tx1[((size_t)node << 7) + c]  =
        make_uint2(pack_hilo(ax), pack_hilo(ay));
    *(uint2*)&sagg[((size_t)node << 7) + c] =
        make_uint2(pack_hilo(sx * inv), pack_hilo(sy * inv));
}

// ---- split-bf16 MFMA GEMM (no LDS, no barriers) ----------------------------
// Wave tile 32 rows (2 m-frags) x 64 cols (4 n-frags); block 2m x 2n waves =
// 64 rows x 128 cols; grid M/64 = 625. Compile-time K, fully unrolled; VGPR
// budget 256 (lb 256,2) lets the scheduler hoist multiple k-steps of loads.

template<bool F32, int K>
__device__ __forceinline__ void gemm_part(
    const void* Av, const uint32_t* __restrict__ Wt,
    int rbase, int cbase, int l15, int kg, f32x4 accA[4], f32x4 accB[4])
{
    #pragma unroll
    for (int k = 0; k < K; k += 32) {
        FragPair Af0, Af1;
        if constexpr (F32) {
            Af0 = cvt_frag_f32((const float*)Av + (size_t)(rbase + l15) * K + k + kg * 8);
            Af1 = cvt_frag_f32((const float*)Av + (size_t)(rbase + 16 + l15) * K + k + kg * 8);
        } else {
            Af0 = load_packed_frag((const uint32_t*)Av + (size_t)(rbase + l15) * K + k + kg * 8);
            Af1 = load_packed_frag((const uint32_t*)Av + (size_t)(rbase + 16 + l15) * K + k + kg * 8);
        }
        #pragma unroll
        for (int n = 0; n < 4; ++n) {
            const FragPair Bf =
                load_packed_frag(Wt + (size_t)(cbase + n * 16 + l15) * K + k + kg * 8);
            accA[n] = __builtin_amdgcn_mfma_f32_16x16x32_bf16(Af0.hi, Bf.hi, accA[n], 0, 0, 0);
            accA[n] = __builtin_amdgcn_mfma_f32_16x16x32_bf16(Af0.hi, Bf.lo, accA[n], 0, 0, 0);
            accA[n] = __builtin_amdgcn_mfma_f32_16x16x32_bf16(Af0.lo, Bf.hi, accA[n], 0, 0, 0);
            accB[n] = __builtin_amdgcn_mfma_f32_16x16x32_bf16(Af1.hi, Bf.hi, accB[n], 0, 0, 0);
            accB[n] = __builtin_amdgcn_mfma_f32_16x16x32_bf16(Af1.hi, Bf.lo, accB[n], 0, 0, 0);
            accB[n] = __builtin_amdgcn_mfma_f32_16x16x32_bf16(Af1.lo, Bf.hi, accB[n], 0, 0, 0);
        }
    }
}

// NPARTS=1: out = A1@W1 + b1
// NPARTS=3: out = leaky(A1@W1 + A2@W2 + b1) + leaky(A3@W3 + b2)
template<int NPARTS, bool AF32, int K1>
__global__ __launch_bounds__(256, 2) void gemm_mfma(
    const void* __restrict__ A1, const uint32_t* __restrict__ Wt1,
    const uint32_t* __restrict__ A2, const uint32_t* __restrict__ Wt2,
    const uint32_t* __restrict__ A3, const uint32_t* __restrict__ Wt3,
    const float* __restrict__ b1, const float* __restrict__ b2,
    uint32_t* __restrict__ out, int M)
{
    const int tid  = threadIdx.x;
    const int lane = tid & 63;
    const int w    = tid >> 6;
    const int mw   = w >> 1, nw = w & 1;
    const int l15  = lane & 15;
    const int kg   = lane >> 4;
    const int rbase = blockIdx.x * 64 + mw * 32;  // M divisible by 64
    const int cbase = nw * 64;

    f32x4 acc0[4], acc1[4];
    #pragma unroll
    for (int n = 0; n < 4; ++n) { acc0[n] = (f32x4)0.f; acc1[n] = (f32x4)0.f; }

    gemm_part<AF32, K1>(A1, Wt1, rbase, cbase, l15, kg, acc0, acc1);

    if constexpr (NPARTS == 3) {
        gemm_part<false, 128>(A2, Wt2, rbase, cbase, l15, kg, acc0, acc1);
        f32x4 accB0[4], accB1[4];
        #pragma unroll
        for (int n = 0; n < 4; ++n) { accB0[n] = (f32x4)0.f; accB1[n] = (f32x4)0.f; }
        gemm_part<false, 128>(A3, Wt3, rbase, cbase, l15, kg, accB0, accB1);

        #pragma unroll
        for (int n = 0; n < 4; ++n) {
            const int col = cbase + n * 16 + l15;
            const float bb1 = b1[col], bb2 = b2[col];
            #pragma unroll
            for (int r = 0; r < 4; ++r) {
                const int row0 = rbase + kg * 4 + r;
                float v0 = leaky01(acc0[n][r] + bb1) + leaky01(accB0[n][r] + bb2);
                float v1 = leaky01(acc1[n][r] + bb1) + leaky01(accB1[n][r] + bb2);
                out[(size_t)row0 * 128 + col]        = pack_hilo(v0);
                out[(size_t)(row0 + 16) * 128 + col] = pack_hilo(v1);
            }
        }
    } else {
        #pragma unroll
        for (int n = 0; n < 4; ++n) {
            const int col = cbase + n * 16 + l15;
            const float bb1 = b1[col];
            #pragma unroll
            for (int r = 0; r < 4; ++r) {
                const int row0 = rbase + kg * 4 + r;
                out[(size_t)row0 * 128 + col]        = pack_hilo(acc0[n][r] + bb1);
                out[(size_t)(row0 + 16) * 128 + col] = pack_hilo(acc1[n][r] + bb1);
            }
        }
    }
    (void)M;
}

// ---- classifier: split-bf16 MFMA + fused log_softmax -----------------------
// Wt padded to 48 cols (cols 40..47 zero). Block = 4 waves x 16 rows = 64
// rows (grid 625). C/D layout col=n*16+l15, row=kg*4+r: a full logit row
// lives in one 16-lane group -> shfl_xor{1,2,4,8} row reductions, no LDS.

__global__ __launch_bounds__(256) void cls_mfma(
    const uint32_t* __restrict__ x2, const uint32_t* __restrict__ Wt,
    const float* __restrict__ bias, float* __restrict__ out, int M)
{
    const int tid  = threadIdx.x;
    const int lane = tid & 63;
    const int w    = tid >> 6;
    const int l15  = lane & 15;
    const int kg   = lane >> 4;
    const int rbase = blockIdx.x * 64 + w * 16;   // M divisible by 64

    f32x4 acc[3];
    #pragma unroll
    for (int n = 0; n < 3; ++n) acc[n] = (f32x4)0.f;

    const int arow = rbase + l15;
    #pragma unroll
    for (int k = 0; k < 128; k += 32) {
        const FragPair Af = load_packed_frag(x2 + (size_t)arow * 128 + k + kg * 8);
        #pragma unroll
        for (int n = 0; n < 3; ++n) {
            const FragPair Bf =
                load_packed_frag(Wt + (size_t)(n * 16 + l15) * 128 + k + kg * 8);
            acc[n] = __builtin_amdgcn_mfma_f32_16x16x32_bf16(Af.hi, Bf.hi, acc[n], 0, 0, 0);
            acc[n] = __builtin_amdgcn_mfma_f32_16x16x32_bf16(Af.hi, Bf.lo, acc[n], 0, 0, 0);
            acc[n] = __builtin_amdgcn_mfma_f32_16x16x32_bf16(Af.lo, Bf.hi, acc[n], 0, 0, 0);
        }
    }

    const bool v2 = (l15 < 8);                   // col 32+l15 < 40
    const float bv0 = bias[l15];
    const float bv1 = bias[16 + l15];
    const float bv2 = v2 ? bias[32 + l15] : 0.f;

    #pragma unroll
    for (int r = 0; r < 4; ++r) {
        const int row = rbase + kg * 4 + r;
        float x0 = acc[0][r] + bv0;
        float x1 = acc[1][r] + bv1;
        float x2v = v2 ? (acc[2][r] + bv2) : -INFINITY;
        float mx = fmaxf(fmaxf(x0, x1), x2v);
        #pragma unroll
        for (int off = 1; off < 16; off <<= 1)
            mx = fmaxf(mx, __shfl_xor(mx, off));
        float s = __expf(x0 - mx) + __expf(x1 - mx) + (v2 ? __expf(x2v - mx) : 0.f);
        #pragma unroll
        for (int off = 1; off < 16; off <<= 1)
            s += __shfl_xor(s, off);
        const float ls = logf(s);
        if (row < M) {
            float* op = &out[(size_t)row * 40];
            op[l15]      = x0 - mx - ls;
            op[16 + l15] = x1 - mx - ls;
            if (v2) op[32 + l15] = x2v - mx - ls;
        }
    }
}

// ---------------------------------------------------------------------------

extern "C" void kernel_launch(void* const* d_in, const int* in_sizes, int n_in,
                              void* d_out, int out_size, void* d_ws, size_t ws_size,
                              hipStream_t stream)
{
    const float* x        = (const float*)d_in[0];
    const int*   ei       = (const int*)d_in[1];
    const float* ew       = (const float*)d_in[2];
    const float* pre_w1   = (const float*)d_in[3];
    const float* pre_b1   = (const float*)d_in[4];
    const float* cheb_w01 = (const float*)d_in[5];
    const float* cheb_w11 = (const float*)d_in[6];
    const float* cheb_b1  = (const float*)d_in[7];
    const float* sage_w1  = (const float*)d_in[8];
    const float* sage_b1  = (const float*)d_in[9];
    const float* lin_w1   = (const float*)d_in[10];
    const float* lin_b1   = (const float*)d_in[11];
    const float* pre_w2   = (const float*)d_in[12];
    const float* pre_b2   = (const float*)d_in[13];
    const float* cheb_w02 = (const float*)d_in[14];
    const float* cheb_w12 = (const float*)d_in[15];
    const float* cheb_b2  = (const float*)d_in[16];
    const float* sage_w2  = (const float*)d_in[17];
    const float* sage_b2  = (const float*)d_in[18];
    const float* lin_w2   = (const float*)d_in[19];
    const float* lin_b2   = (const float*)d_in[20];
    const float* cls_w    = (const float*)d_in[21];
    const float* cls_b    = (const float*)d_in[22];

    const int H    = 128;
    const int F_IN = in_sizes[3] / H;       // 512
    const int N    = in_sizes[0] / F_IN;    // 40000
    const int E    = in_sizes[2];           // 640000
    const int* src = ei;
    const int* dst = ei + E;

    // workspace carve-up (256B aligned)
    char* p = (char*)d_ws;
    auto alloc = [&](size_t bytes) -> void* {
        void* r = (void*)p;
        p += (bytes + 255) & ~(size_t)255;
        return r;
    };
    uint32_t* buf0 = (uint32_t*)alloc((size_t)N * 128 * 4);   // packed activations
    uint32_t* buf1 = (uint32_t*)alloc((size_t)N * 128 * 4);
    uint32_t* buf2 = (uint32_t*)alloc((size_t)N * 128 * 4);
    uint32_t* buf3 = (uint32_t*)alloc((size_t)N * 128 * 4);
    float* deg     = (float*)alloc((size_t)N * 4);
    float* dis     = (float*)alloc((size_t)N * 4);
    float* loop_w  = (float*)alloc((size_t)N * 4);
    int*   cnt     = (int*)alloc((size_t)N * 4);
    int*   offs    = (int*)alloc((size_t)(N + 1) * 4);
    int*   cursor  = (int*)alloc((size_t)N * 4);
    int*   bsum    = (int*)alloc(64 * 4);
    int*   bbase   = (int*)alloc(64 * 4);
    int*   slot_src  = (int*)alloc((size_t)E * 4);
    float* slot_nrm  = (float*)alloc((size_t)E * 4);
    float* slot_we   = (float*)alloc((size_t)E * 4);
    float* Wm1 = (float*)alloc((size_t)H * H * 4);    // lin_w1 @ pre_w2 (fp32)
    float* bm1 = (float*)alloc((size_t)H * 4);
    float* Wm2 = (float*)alloc((size_t)H * 40 * 4);   // lin_w2 @ cls_w (fp32)
    float* bm2 = (float*)alloc((size_t)40 * 4);
    uint32_t* wt = (uint32_t*)alloc((size_t)WT_TOTAL * 4);    // packed W^T
    (void)ws_size; (void)n_in; (void)out_size;

    uint32_t* wt_pre  = wt;                 // [128][512]
    uint32_t* wt_cw01 = wt + 65536;
    uint32_t* wt_cw11 = wt_cw01 + 16384;
    uint32_t* wt_sw1  = wt_cw11 + 16384;
    uint32_t* wt_Wm1  = wt_sw1  + 16384;
    uint32_t* wt_cw02 = wt_Wm1  + 16384;
    uint32_t* wt_cw12 = wt_cw02 + 16384;
    uint32_t* wt_sw2  = wt_cw12 + 16384;
    uint32_t* wt_cls  = wt_sw2  + 16384;    // [48][128]

    const int nb_n = (N + 255) / 256;
    const int nb_e = (E + 255) / 256;
    const int nb_w = (N + 3) / 4;           // wave-per-node kernels
    const int nb_g = (N + 63) / 64;         // MFMA GEMM blocks (625)
    const int nb_s = (N + 1023) / 1024;     // scan blocks (40)
    const int nb_c = (N + 63) / 64;         // cls blocks (625)

    // graph preprocessing + weight merge/convert
    init_nodes<<<nb_n, 256, 0, stream>>>(deg, cnt, loop_w, N);
    edge_pass1<<<nb_e, 256, 0, stream>>>(src, dst, ew, deg, cnt, loop_w, E);
    scan_blocks<<<nb_s, 1024, 0, stream>>>(cnt, deg, offs, bsum, dis, N);
    scan_tops<<<1, 64, 0, stream>>>(bsum, bbase, offs, nb_s, N);
    scan_add<<<nb_n, 256, 0, stream>>>(offs, cursor, bbase, N);
    edge_pass2<<<nb_e, 256, 0, stream>>>(src, dst, ew, dis, cursor,
                                         slot_src, slot_nrm, slot_we, E);
    merge_weights<<<((H + 1) * H + 255) / 256, 256, 0, stream>>>(
        lin_w1, pre_w2, lin_b1, pre_b2, Wm1, bm1, H, H);
    merge_weights<<<((H + 1) * 40 + 255) / 256, 256, 0, stream>>>(
        lin_w2, cls_w, lin_b2, cls_b, Wm2, bm2, H, 40);
    convert_weights<<<(WT_TOTAL + 255) / 256, 256, 0, stream>>>(
        pre_w1, cheb_w01, cheb_w11, sage_w1, Wm1, cheb_w02, cheb_w12, sage_w2,
        Wm2, wt);

    // ---- cell 1 ----
    gemm_mfma<1, true, 512><<<nb_g, 256, 0, stream>>>(
        x, wt_pre, nullptr, nullptr, nullptr, nullptr,
        pre_b1, nullptr, buf0, N);
    aggregate_packed<<<nb_w, 256, 0, stream>>>(buf0, offs, slot_src, slot_nrm,
                                               slot_we, loop_w, cnt, buf1, buf2, N);
    gemm_mfma<3, false, 128><<<nb_g, 256, 0, stream>>>(
        buf0, wt_cw01, buf1, wt_cw11, buf2, wt_sw1,
        cheb_b1, sage_b1, buf3, N);
    gemm_mfma<1, false, 128><<<nb_g, 256, 0, stream>>>(
        buf3, wt_Wm1, nullptr, nullptr, nullptr, nullptr,
        bm1, nullptr, buf0, N);

    // ---- cell 2 ----
    aggregate_packed<<<nb_w, 256, 0, stream>>>(buf0, offs, slot_src, slot_nrm,
                                               slot_we, loop_w, cnt, buf1, buf2, N);
    gemm_mfma<3, false, 128><<<nb_g, 256, 0, stream>>>(
        buf0, wt_cw02, buf1, wt_cw12, buf2, wt_sw2,
        cheb_b2, sage_b2, buf3, N);

    // classifier (merged lin2+cls, MFMA) + fused log_softmax -> d_out
    cls_mfma<<<nb_c, 256, 0, stream>>>(buf3, wt_cls, bm2, (float*)d_out, N);
}